// Round 1
// baseline (487.881 us; speedup 1.0000x reference)
//
#include <hip/hip_runtime.h>

// ChemResBlock: A=2048 atoms, D=64 depth, F=12 filter taps.
// out[a,o] = sum_{n,f} conn[a][n*12+f] * Gt[o][n*12+f] + bterm[a,o]
// conn (2048 x 24576 fp32) is contiguous in exactly this K order.

#define A_N 2048
#define D_N 64
#define F_N 12
#define K_TOTAL (A_N * F_N)        // 24576
#define NSPLIT 16
#define KSEG (K_TOTAL / NSPLIT)    // 1536
#define BK 64
#define LDB 72                     // bf16 elems per LDS row (64 + 8 pad -> 144 B)

typedef short short8 __attribute__((ext_vector_type(8)));
typedef float f32x4 __attribute__((ext_vector_type(4)));

// pack two floats to bf16 pair with round-to-nearest-even
__device__ __forceinline__ unsigned pk_bf16(float a, float b) {
  unsigned ua = __float_as_uint(a);
  unsigned ub = __float_as_uint(b);
  ua += 0x7fffu + ((ua >> 16) & 1u);
  ub += 0x7fffu + ((ub >> 16) & 1u);
  return (ua >> 16) | (ub & 0xffff0000u);
}

// ---------------- prep: x (2048x64) -> xt (64x2048) ----------------
__global__ void k_transpose_x(const float* __restrict__ x, float* __restrict__ xt) {
  __shared__ float ld[64][65];
  int m0 = blockIdx.x * 64;
  int t = threadIdx.x;
  int r = t >> 2, cq = (t & 3) * 16;
  const float4* src = (const float4*)(x + (size_t)(m0 + r) * 64 + cq);
#pragma unroll
  for (int i = 0; i < 4; ++i) {
    float4 v = src[i];
    ld[r][cq + i * 4 + 0] = v.x;
    ld[r][cq + i * 4 + 1] = v.y;
    ld[r][cq + i * 4 + 2] = v.z;
    ld[r][cq + i * 4 + 3] = v.w;
  }
  __syncthreads();
  int c = t >> 2, ml0 = (t & 3) * 16;
  float4* dst = (float4*)(xt + (size_t)c * 2048 + m0 + ml0);
#pragma unroll
  for (int i = 0; i < 4; ++i) {
    float4 v;
    v.x = ld[ml0 + i * 4 + 0][c];
    v.y = ld[ml0 + i * 4 + 1][c];
    v.z = ld[ml0 + i * 4 + 2][c];
    v.w = ld[ml0 + i * 4 + 3][c];
    dst[i] = v;
  }
}

// ---------------- prep: bterm_t[o][a] for both filter sets ----------------
// bt[o][a] = sum_{f,j} bond[a][f][j] * filt[o][f][64+j]
__global__ void k_bterm(const float* __restrict__ bond, const float* __restrict__ f0,
                        const float* __restrict__ f1, float* __restrict__ bt0,
                        float* __restrict__ bt1) {
  int a = blockIdx.x * 64 + (threadIdx.x & 63);
  int o = blockIdx.y * 4 + (threadIdx.x >> 6);
  float s0 = 0.f, s1 = 0.f;
#pragma unroll
  for (int f = 0; f < F_N; ++f) {
#pragma unroll
    for (int j = 0; j < 2; ++j) {
      float bv = bond[a * 24 + f * 2 + j];
      s0 += bv * f0[o * 792 + f * 66 + 64 + j];
      s1 += bv * f1[o * 792 + f * 66 + 64 + j];
    }
  }
  bt0[o * 2048 + a] = s0;
  bt1[o * 2048 + a] = s1;
}

// ---------------- per-layer: Gt[o][n*12+f] = sum_d vt[d][n]*filt[o][f][d] ----------------
__global__ void k_g(const float* __restrict__ vt, const float* __restrict__ filt,
                    unsigned* __restrict__ gt /* bf16 pairs */) {
  __shared__ float W[12][64];
  int o = blockIdx.y;
  int t = threadIdx.x;
  for (int i = t; i < 768; i += 256) W[i >> 6][i & 63] = filt[o * 792 + (i >> 6) * 66 + (i & 63)];
  __syncthreads();
  int n = blockIdx.x * 256 + t;
  float acc[12] = {0.f, 0.f, 0.f, 0.f, 0.f, 0.f, 0.f, 0.f, 0.f, 0.f, 0.f, 0.f};
#pragma unroll 4
  for (int d = 0; d < 64; ++d) {
    float v = vt[d * 2048 + n];
#pragma unroll
    for (int f = 0; f < F_N; ++f) acc[f] += v * W[f][d];
  }
  unsigned* dst = gt + ((size_t)o * K_TOTAL + n * 12) / 2;
#pragma unroll
  for (int i = 0; i < 6; ++i) dst[i] = pk_bf16(acc[2 * i], acc[2 * i + 1]);
}

// ---------------- per-layer: split-K GEMM, partials[ks][o][m] ----------------
// block: 64 conn rows (MFMA n-dim) x all 64 o (MFMA m'-dim), K chunk = 1536
__launch_bounds__(256, 2)
__global__ void k_big(const float* __restrict__ conn, const unsigned short* __restrict__ gt,
                      float* __restrict__ part) {
  __shared__ unsigned short smem[2 * 64 * LDB];
  unsigned short* As = smem;             // Gt tile: [o 64][k 64+pad]
  unsigned short* Bs = smem + 64 * LDB;  // conn tile: [m 64][k 64+pad]

  int mt = blockIdx.x;  // 0..31
  int ks = blockIdx.y;  // 0..NSPLIT-1
  int r0 = mt * 64;
  int k0 = ks * KSEG;
  int t = threadIdx.x, lane = t & 63, wave = t >> 6;
  int o0 = (wave & 1) * 32, n0 = (wave >> 1) * 32;

  f32x4 zero = {0.f, 0.f, 0.f, 0.f};
  f32x4 acc[2][2];
  acc[0][0] = zero; acc[0][1] = zero; acc[1][0] = zero; acc[1][1] = zero;

  int srow = t >> 2, scq = (t & 3) * 16;
  const float* connp = conn + (size_t)(r0 + srow) * K_TOTAL + k0 + scq;
  const unsigned short* gtp = gt + (size_t)srow * K_TOTAL + k0 + scq;
  unsigned short* bsw = Bs + srow * LDB + scq;
  unsigned short* asw = As + srow * LDB + scq;

  int arow = (lane & 15) * LDB + ((lane >> 4) << 3);

  for (int kb = 0; kb < KSEG / BK; ++kb) {
    float4 c0 = *(const float4*)(connp + 0);
    float4 c1 = *(const float4*)(connp + 4);
    float4 c2 = *(const float4*)(connp + 8);
    float4 c3 = *(const float4*)(connp + 12);
    uint4 g0 = *(const uint4*)(gtp);
    uint4 g1 = *((const uint4*)(gtp) + 1);
    __syncthreads();
    uint4 wb0, wb1;
    wb0.x = pk_bf16(c0.x, c0.y); wb0.y = pk_bf16(c0.z, c0.w);
    wb0.z = pk_bf16(c1.x, c1.y); wb0.w = pk_bf16(c1.z, c1.w);
    wb1.x = pk_bf16(c2.x, c2.y); wb1.y = pk_bf16(c2.z, c2.w);
    wb1.z = pk_bf16(c3.x, c3.y); wb1.w = pk_bf16(c3.z, c3.w);
    *(uint4*)(bsw) = wb0;
    *(uint4*)(bsw + 8) = wb1;
    *(uint4*)(asw) = g0;
    *(uint4*)(asw + 8) = g1;
    __syncthreads();
#pragma unroll
    for (int kk = 0; kk < 2; ++kk) {
      int kof = kk * 32 + arow;
      short8 a0 = *(const short8*)(As + o0 * LDB + kof);
      short8 a1 = *(const short8*)(As + (o0 + 16) * LDB + kof);
      short8 b0 = *(const short8*)(Bs + n0 * LDB + kof);
      short8 b1 = *(const short8*)(Bs + (n0 + 16) * LDB + kof);
      acc[0][0] = __builtin_amdgcn_mfma_f32_16x16x32_bf16(a0, b0, acc[0][0], 0, 0, 0);
      acc[0][1] = __builtin_amdgcn_mfma_f32_16x16x32_bf16(a0, b1, acc[0][1], 0, 0, 0);
      acc[1][0] = __builtin_amdgcn_mfma_f32_16x16x32_bf16(a1, b0, acc[1][0], 0, 0, 0);
      acc[1][1] = __builtin_amdgcn_mfma_f32_16x16x32_bf16(a1, b1, acc[1][1], 0, 0, 0);
    }
    connp += BK;
    gtp += BK;
  }

  // D layout (16x16x32): col(n=conn row) = lane&15, row(o) = (lane>>4)*4 + reg
  float* pp = part + (size_t)ks * (64 * 2048);
  int quad = (lane >> 4) << 2;
  int mcol = lane & 15;
#pragma unroll
  for (int i = 0; i < 2; ++i) {
#pragma unroll
    for (int j = 0; j < 2; ++j) {
#pragma unroll
      for (int r = 0; r < 4; ++r) {
        int o = o0 + i * 16 + quad + r;
        int m = r0 + n0 + j * 16 + mcol;
        pp[o * 2048 + m] = acc[i][j][r];
      }
    }
  }
}

// ---------------- per-layer epilogue: sum partials + bterm (+x) + relu ----------------
__global__ void k_reduce(const float* __restrict__ part, const float* __restrict__ bt,
                         const float* __restrict__ xt, float* __restrict__ curt,
                         float* __restrict__ outp, int residual, int final_layer) {
  int idx = blockIdx.x * 256 + threadIdx.x;  // 0 .. 64*2048-1, layout [o][m]
  float s = bt[idx];
#pragma unroll
  for (int sI = 0; sI < NSPLIT; ++sI) s += part[(size_t)sI * (64 * 2048) + idx];
  if (residual) s += xt[idx];
  s = fmaxf(s, 0.f);
  curt[idx] = s;
  if (final_layer) {
    int o = idx >> 11, m = idx & 2047;
    outp[m * 64 + o] = s;
  }
}

extern "C" void kernel_launch(void* const* d_in, const int* in_sizes, int n_in,
                              void* d_out, int out_size, void* d_ws, size_t ws_size,
                              hipStream_t stream) {
  const float* x    = (const float*)d_in[0];  // (2048, 64)
  const float* conn = (const float*)d_in[1];  // (2048, 2048, 12)
  const float* bond = (const float*)d_in[2];  // (2048, 12, 2)
  const float* f0   = (const float*)d_in[3];  // (64, 12, 66)
  const float* f1   = (const float*)d_in[4];
  float* out = (float*)d_out;                 // (2048, 64)

  char* ws = (char*)d_ws;
  float* xt   = (float*)(ws + 0);              // 64x2048 fp32          512 KB
  float* curt = (float*)(ws + 524288);         // 64x2048 fp32          512 KB
  float* bt0  = (float*)(ws + 1048576);        // 64x2048 fp32          512 KB
  float* bt1  = (float*)(ws + 1572864);        // 64x2048 fp32          512 KB
  unsigned short* gt = (unsigned short*)(ws + 2097152);  // 64x24576 bf16  3 MB
  float* part = (float*)(ws + 5242880);        // 16 x 64x2048 fp32     8 MB
  // total 13,631,488 bytes of d_ws used

  k_transpose_x<<<32, 256, 0, stream>>>(x, xt);
  k_bterm<<<dim3(32, 16), 256, 0, stream>>>(bond, f0, f1, bt0, bt1);

  for (int layer = 0; layer < 4; ++layer) {
    const float* filt = (layer < 2) ? f0 : f1;
    const float* bt   = (layer < 2) ? bt0 : bt1;
    const float* vin  = (layer == 0) ? xt : curt;
    k_g<<<dim3(8, 64), 256, 0, stream>>>(vin, filt, (unsigned*)gt);
    k_big<<<dim3(32, NSPLIT), 256, 0, stream>>>(conn, gt, part);
    k_reduce<<<512, 256, 0, stream>>>(part, bt, xt, curt, out, layer & 1, layer == 3);
  }
}